// Round 1
// baseline (722.098 us; speedup 1.0000x reference)
//
#include <hip/hip_runtime.h>

typedef short bf16x8 __attribute__((ext_vector_type(8)));
typedef float f32x4 __attribute__((ext_vector_type(4)));
typedef unsigned short u16;

#define MFMA16x16x32(a, b, c) __builtin_amdgcn_mfma_f32_16x16x32_bf16((a), (b), (c), 0, 0, 0)

// Problem constants
#define BATCH 4
#define SEQ 2048
#define DMODEL 1024
#define NHEADS 16
#define DHEAD 64
#define MROWS (BATCH * SEQ)  // 8192

__device__ __forceinline__ u16 f2bf(float f) {
  unsigned u = __builtin_bit_cast(unsigned, f);
  u += 0x7fffu + ((u >> 16) & 1u);  // RNE
  return (u16)(u >> 16);
}

// ---------------- fp32 -> bf16 conversion ----------------
__global__ void cvt_f32_bf16(const float* __restrict__ src, u16* __restrict__ dst, int n4) {
  int i = blockIdx.x * blockDim.x + threadIdx.x;
  if (i < n4) {
    float4 v = reinterpret_cast<const float4*>(src)[i];
    ushort4 o;
    o.x = f2bf(v.x); o.y = f2bf(v.y); o.z = f2bf(v.z); o.w = f2bf(v.w);
    reinterpret_cast<ushort4*>(dst)[i] = o;
  }
}

// ---------------- GEMM: C = A @ B^T ----------------
// A: [M, 1024] bf16 row-major, B: [1024, 1024] bf16 row-major (rows = output cols)
// MODE 0: store bf16 to [B,H,L,dh]   (Q, K)
// MODE 1: store bf16 to [B,H,dh,L]   (V transposed)
// MODE 2: store fp32 to [M, 1024]    (final output)
template <int MODE>
__global__ __launch_bounds__(256) void gemm_bt(const u16* __restrict__ A,
                                               const u16* __restrict__ Bm,
                                               void* __restrict__ dst) {
  constexpr int K = 1024;
  constexpr int LSTR = 72;  // padded LDS row stride (shorts); 144B, 16B-aligned, bank-stride 36
  __shared__ u16 As[128 * LSTR];
  __shared__ u16 Bs[128 * LSTR];
  const int tid = threadIdx.x;
  const int lane = tid & 63;
  const int w = tid >> 6;
  const int wr = w >> 1, wc = w & 1;
  const int quad = lane >> 4, l16 = lane & 15;
  const int row0 = blockIdx.y * 128, col0 = blockIdx.x * 128;

  f32x4 acc[4][4] = {};

  for (int k0 = 0; k0 < K; k0 += 64) {
    __syncthreads();  // previous iteration's frag reads done before overwrite
#pragma unroll
    for (int i = 0; i < 4; i++) {
      int ch = tid + i * 256;          // 1024 16B-chunks per tile
      int r = ch >> 3, cg = (ch & 7) * 8;
      *reinterpret_cast<bf16x8*>(&As[r * LSTR + cg]) =
          *reinterpret_cast<const bf16x8*>(&A[(row0 + r) * K + k0 + cg]);
      *reinterpret_cast<bf16x8*>(&Bs[r * LSTR + cg]) =
          *reinterpret_cast<const bf16x8*>(&Bm[(col0 + r) * K + k0 + cg]);
    }
    __syncthreads();
#pragma unroll
    for (int ks = 0; ks < 2; ks++) {
      bf16x8 af[4], bfr[4];
#pragma unroll
      for (int i = 0; i < 4; i++)
        af[i] = *reinterpret_cast<const bf16x8*>(
            &As[(wr * 64 + i * 16 + l16) * LSTR + ks * 32 + quad * 8]);
#pragma unroll
      for (int j = 0; j < 4; j++)
        bfr[j] = *reinterpret_cast<const bf16x8*>(
            &Bs[(wc * 64 + j * 16 + l16) * LSTR + ks * 32 + quad * 8]);
#pragma unroll
      for (int i = 0; i < 4; i++)
#pragma unroll
        for (int j = 0; j < 4; j++)
          acc[i][j] = MFMA16x16x32(af[i], bfr[j], acc[i][j]);
    }
  }

  // Epilogue. C/D layout: row = quad*4 + r, col = l16 (m89-verified)
#pragma unroll
  for (int i = 0; i < 4; i++)
#pragma unroll
    for (int j = 0; j < 4; j++)
#pragma unroll
      for (int r = 0; r < 4; r++) {
        int row = row0 + wr * 64 + i * 16 + quad * 4 + r;  // 0..8191  (b*2048 + l)
        int col = col0 + wc * 64 + j * 16 + l16;           // 0..1023  (h*64 + d)
        float v = acc[i][j][r];
        if constexpr (MODE == 0) {
          u16* q = (u16*)dst;
          int bh = ((row >> 11) << 4) | (col >> 6);
          q[(bh * SEQ + (row & 2047)) * DHEAD + (col & 63)] = f2bf(v);
        } else if constexpr (MODE == 1) {
          u16* q = (u16*)dst;
          int bh = ((row >> 11) << 4) | (col >> 6);
          q[(bh * DHEAD + (col & 63)) * SEQ + (row & 2047)] = f2bf(v);
        } else {
          ((float*)dst)[row * DMODEL + col] = v;
        }
      }
}

// ---------------- Flash attention (causal) ----------------
// Q,K: [B*H, L, dh] bf16;  Vt: [B*H, dh, L] bf16;  Ao: [B, L, H*dh] bf16
// Block = 256 thr (4 waves) handles 128 q-rows of one (b,h). Each wave: 32 rows.
// No block-wide barriers in the k-loop (per-wave LDS P region).
__global__ __launch_bounds__(256) void attn_kernel(const u16* __restrict__ Q,
                                                   const u16* __restrict__ Kk,
                                                   const u16* __restrict__ Vt,
                                                   u16* __restrict__ Ao) {
  constexpr int PSTR = 72;  // padded P row stride in shorts
  __shared__ u16 Plds[4 * 16 * PSTR];
  const int lane = threadIdx.x & 63;
  const int w = threadIdx.x >> 6;
  const int quad = lane >> 4, l16 = lane & 15;
  const int bh = blockIdx.x >> 4;  // 0..63
  const int qt = blockIdx.x & 15;
  const int b = bh >> 4, h = bh & 15;
  const u16* Qh = Q + bh * SEQ * DHEAD;
  const u16* Kh = Kk + bh * SEQ * DHEAD;
  const u16* Vh = Vt + bh * DHEAD * SEQ;
  u16* Pw = &Plds[w * 16 * PSTR];
  const int q0w = qt * 128 + w * 32;
  const float scale = 0.125f;  // 1/sqrt(64)

  // Q fragments, resident for whole kernel. A layout: m = l16, k = quad*8+j
  bf16x8 qf[2][2];
#pragma unroll
  for (int rt = 0; rt < 2; rt++)
#pragma unroll
    for (int ks = 0; ks < 2; ks++)
      qf[rt][ks] = *reinterpret_cast<const bf16x8*>(
          &Qh[(q0w + rt * 16 + l16) * DHEAD + ks * 32 + quad * 8]);

  f32x4 o[2][4] = {};
  float m_i[2][4], l_i[2][4];
#pragma unroll
  for (int rt = 0; rt < 2; rt++)
#pragma unroll
    for (int r = 0; r < 4; r++) { m_i[rt][r] = -1e30f; l_i[rt][r] = 0.f; }

  const int nkt = ((q0w + 31) >> 6) + 1;  // k-tiles up to causal diagonal

  for (int kt = 0; kt < nkt; kt++) {
    const int kbase = kt * 64;
#pragma unroll
    for (int rt = 0; rt < 2; rt++) {
      // ---- S = Q K^T for this 16-row tile ----
      f32x4 s[4];
#pragma unroll
      for (int nt = 0; nt < 4; nt++) {
        bf16x8 kf0 = *reinterpret_cast<const bf16x8*>(
            &Kh[(kbase + nt * 16 + l16) * DHEAD + quad * 8]);
        bf16x8 kf1 = *reinterpret_cast<const bf16x8*>(
            &Kh[(kbase + nt * 16 + l16) * DHEAD + 32 + quad * 8]);
        f32x4 z = {0.f, 0.f, 0.f, 0.f};
        z = MFMA16x16x32(qf[rt][0], kf0, z);
        s[nt] = MFMA16x16x32(qf[rt][1], kf1, z);
      }
      // ---- scale + causal mask ----
      float sv[4][4];
#pragma unroll
      for (int nt = 0; nt < 4; nt++)
#pragma unroll
        for (int r = 0; r < 4; r++) {
          int qrow = q0w + rt * 16 + quad * 4 + r;
          int kcol = kbase + nt * 16 + l16;
          sv[nt][r] = (kcol <= qrow) ? s[nt][r] * scale : -1e30f;
        }
      // ---- online softmax (rows live across 16 lanes of each quad) ----
      float mx[4];
#pragma unroll
      for (int r = 0; r < 4; r++)
        mx[r] = fmaxf(fmaxf(sv[0][r], sv[1][r]), fmaxf(sv[2][r], sv[3][r]));
#pragma unroll
      for (int off = 8; off >= 1; off >>= 1)
#pragma unroll
        for (int r = 0; r < 4; r++) mx[r] = fmaxf(mx[r], __shfl_xor(mx[r], off));
      float alpha[4];
#pragma unroll
      for (int r = 0; r < 4; r++) {
        float mnew = fmaxf(m_i[rt][r], mx[r]);
        alpha[r] = __expf(m_i[rt][r] - mnew);
        m_i[rt][r] = mnew;
      }
      float rs[4] = {0.f, 0.f, 0.f, 0.f};
#pragma unroll
      for (int nt = 0; nt < 4; nt++)
#pragma unroll
        for (int r = 0; r < 4; r++) {
          float p = __expf(sv[nt][r] - m_i[rt][r]);  // masked -> exp(-huge) = 0
          sv[nt][r] = p;
          rs[r] += p;
        }
#pragma unroll
      for (int off = 8; off >= 1; off >>= 1)
#pragma unroll
        for (int r = 0; r < 4; r++) rs[r] += __shfl_xor(rs[r], off);
#pragma unroll
      for (int r = 0; r < 4; r++) l_i[rt][r] = l_i[rt][r] * alpha[r] + rs[r];
#pragma unroll
      for (int nt = 0; nt < 4; nt++)
#pragma unroll
        for (int r = 0; r < 4; r++) o[rt][nt][r] *= alpha[r];
      // ---- P: C-layout -> A-layout via per-wave LDS ----
#pragma unroll
      for (int nt = 0; nt < 4; nt++)
#pragma unroll
        for (int r = 0; r < 4; r++)
          Pw[(quad * 4 + r) * PSTR + nt * 16 + l16] = f2bf(sv[nt][r]);
      asm volatile("s_waitcnt lgkmcnt(0)" ::: "memory");
      bf16x8 pa0 = *reinterpret_cast<const bf16x8*>(&Pw[l16 * PSTR + quad * 8]);
      bf16x8 pa1 = *reinterpret_cast<const bf16x8*>(&Pw[l16 * PSTR + 32 + quad * 8]);
      // ---- O += P V  (B operand from V^T rows: contiguous) ----
#pragma unroll
      for (int nt2 = 0; nt2 < 4; nt2++) {
        bf16x8 vf0 = *reinterpret_cast<const bf16x8*>(
            &Vh[(nt2 * 16 + l16) * SEQ + kbase + quad * 8]);
        bf16x8 vf1 = *reinterpret_cast<const bf16x8*>(
            &Vh[(nt2 * 16 + l16) * SEQ + kbase + 32 + quad * 8]);
        o[rt][nt2] = MFMA16x16x32(pa0, vf0, o[rt][nt2]);
        o[rt][nt2] = MFMA16x16x32(pa1, vf1, o[rt][nt2]);
      }
      asm volatile("s_waitcnt lgkmcnt(0)" ::: "memory");  // drain reads before Pw reuse
    }
  }

  // ---- epilogue: O / l -> Ao [B, L, H*dh] bf16 ----
#pragma unroll
  for (int rt = 0; rt < 2; rt++)
#pragma unroll
    for (int nt2 = 0; nt2 < 4; nt2++)
#pragma unroll
      for (int r = 0; r < 4; r++) {
        int qrow = q0w + rt * 16 + quad * 4 + r;
        float v = o[rt][nt2][r] / l_i[rt][r];
        Ao[(b * SEQ + qrow) * DMODEL + h * DHEAD + nt2 * 16 + l16] = f2bf(v);
      }
}

// ---------------- launch ----------------
extern "C" void kernel_launch(void* const* d_in, const int* in_sizes, int n_in,
                              void* d_out, int out_size, void* d_ws, size_t ws_size,
                              hipStream_t stream) {
  const float* x = (const float*)d_in[0];
  const float* Wq = (const float*)d_in[1];
  const float* Wk = (const float*)d_in[2];
  const float* Wv = (const float*)d_in[3];
  const float* Wo = (const float*)d_in[4];
  float* out = (float*)d_out;

  // workspace layout (all bf16 = u16)
  u16* xb  = (u16*)d_ws;                    // 8192*1024
  u16* wqb = xb  + MROWS * DMODEL;          // 1024*1024
  u16* wkb = wqb + DMODEL * DMODEL;
  u16* wvb = wkb + DMODEL * DMODEL;
  u16* wob = wvb + DMODEL * DMODEL;
  u16* qb  = wob + DMODEL * DMODEL;         // [B,H,L,dh]
  u16* kb  = qb  + MROWS * DMODEL;
  u16* vtb = kb  + MROWS * DMODEL;          // [B,H,dh,L]
  u16* aob = vtb + MROWS * DMODEL;          // [B,L,D]

  // converts
  {
    int n4 = MROWS * DMODEL / 4;
    cvt_f32_bf16<<<n4 / 256, 256, 0, stream>>>(x, xb, n4);
    int w4 = DMODEL * DMODEL / 4;
    cvt_f32_bf16<<<w4 / 256, 256, 0, stream>>>(Wq, wqb, w4);
    cvt_f32_bf16<<<w4 / 256, 256, 0, stream>>>(Wk, wkb, w4);
    cvt_f32_bf16<<<w4 / 256, 256, 0, stream>>>(Wv, wvb, w4);
    cvt_f32_bf16<<<w4 / 256, 256, 0, stream>>>(Wo, wob, w4);
  }

  dim3 ggrid(DMODEL / 128, MROWS / 128);  // (8, 64)
  gemm_bt<0><<<ggrid, 256, 0, stream>>>(xb, wqb, (void*)qb);
  gemm_bt<0><<<ggrid, 256, 0, stream>>>(xb, wkb, (void*)kb);
  gemm_bt<1><<<ggrid, 256, 0, stream>>>(xb, wvb, (void*)vtb);

  attn_kernel<<<BATCH * NHEADS * (SEQ / 128), 256, 0, stream>>>(qb, kb, vtb, aob);

  gemm_bt<2><<<ggrid, 256, 0, stream>>>(aob, wob, (void*)out);
}

// Round 2
// 290.067 us; speedup vs baseline: 2.4894x; 2.4894x over previous
//
#include <hip/hip_runtime.h>

typedef short bf16x8 __attribute__((ext_vector_type(8)));
typedef float f32x4 __attribute__((ext_vector_type(4)));
typedef unsigned short u16;

#define MFMA16x16x32(a, b, c) __builtin_amdgcn_mfma_f32_16x16x32_bf16((a), (b), (c), 0, 0, 0)

// Problem constants
#define BATCH 4
#define SEQ 2048
#define DMODEL 1024
#define NHEADS 16
#define DHEAD 64
#define MROWS (BATCH * SEQ)  // 8192

__device__ __forceinline__ u16 f2bf(float f) {
  unsigned u = __builtin_bit_cast(unsigned, f);
  u += 0x7fffu + ((u >> 16) & 1u);  // RNE
  return (u16)(u >> 16);
}

// ---- DPP row reductions (16-lane rows == one quad's l16 group) ----
template <int CTRL>
__device__ __forceinline__ float dppmov(float x) {
  return __builtin_bit_cast(
      float, __builtin_amdgcn_mov_dpp(__builtin_bit_cast(int, x), CTRL, 0xF, 0xF, false));
}
__device__ __forceinline__ float rowmax16(float x) {
  x = fmaxf(x, dppmov<0x128>(x));  // row_ror:8
  x = fmaxf(x, dppmov<0x124>(x));  // row_ror:4
  x = fmaxf(x, dppmov<0x122>(x));  // row_ror:2
  x = fmaxf(x, dppmov<0x121>(x));  // row_ror:1
  return x;
}
__device__ __forceinline__ float rowsum16(float x) {
  x += dppmov<0x128>(x);
  x += dppmov<0x124>(x);
  x += dppmov<0x122>(x);
  x += dppmov<0x121>(x);
  return x;
}

// ---------------- fp32 -> bf16 conversion ----------------
__global__ void cvt_f32_bf16(const float* __restrict__ src, u16* __restrict__ dst, int n4) {
  int i = blockIdx.x * blockDim.x + threadIdx.x;
  if (i < n4) {
    float4 v = reinterpret_cast<const float4*>(src)[i];
    ushort4 o;
    o.x = f2bf(v.x); o.y = f2bf(v.y); o.z = f2bf(v.z); o.w = f2bf(v.w);
    reinterpret_cast<ushort4*>(dst)[i] = o;
  }
}

// ---------------- GEMM: C = A @ B^T ----------------
// MODE 0: store bf16 to [B,H,L,dh]           (K)
// MODE 1: store bf16 to [B,H,dh,L]           (V transposed)
// MODE 2: store fp32 to [M, 1024]            (final output)
// MODE 3: store bf16*0.125 to [B,H,L,dh]     (Q, softmax scale folded in)
template <int MODE>
__global__ __launch_bounds__(256) void gemm_bt(const u16* __restrict__ A,
                                               const u16* __restrict__ Bm,
                                               void* __restrict__ dst) {
  constexpr int K = 1024;
  constexpr int LSTR = 72;
  __shared__ u16 As[128 * LSTR];
  __shared__ u16 Bs[128 * LSTR];
  const int tid = threadIdx.x;
  const int lane = tid & 63;
  const int w = tid >> 6;
  const int wr = w >> 1, wc = w & 1;
  const int quad = lane >> 4, l16 = lane & 15;
  const int row0 = blockIdx.y * 128, col0 = blockIdx.x * 128;

  f32x4 acc[4][4] = {};

  for (int k0 = 0; k0 < K; k0 += 64) {
    __syncthreads();
#pragma unroll
    for (int i = 0; i < 4; i++) {
      int ch = tid + i * 256;
      int r = ch >> 3, cg = (ch & 7) * 8;
      *reinterpret_cast<bf16x8*>(&As[r * LSTR + cg]) =
          *reinterpret_cast<const bf16x8*>(&A[(row0 + r) * K + k0 + cg]);
      *reinterpret_cast<bf16x8*>(&Bs[r * LSTR + cg]) =
          *reinterpret_cast<const bf16x8*>(&Bm[(col0 + r) * K + k0 + cg]);
    }
    __syncthreads();
#pragma unroll
    for (int ks = 0; ks < 2; ks++) {
      bf16x8 af[4], bfr[4];
#pragma unroll
      for (int i = 0; i < 4; i++)
        af[i] = *reinterpret_cast<const bf16x8*>(
            &As[(wr * 64 + i * 16 + l16) * LSTR + ks * 32 + quad * 8]);
#pragma unroll
      for (int j = 0; j < 4; j++)
        bfr[j] = *reinterpret_cast<const bf16x8*>(
            &Bs[(wc * 64 + j * 16 + l16) * LSTR + ks * 32 + quad * 8]);
#pragma unroll
      for (int i = 0; i < 4; i++)
#pragma unroll
        for (int j = 0; j < 4; j++)
          acc[i][j] = MFMA16x16x32(af[i], bfr[j], acc[i][j]);
    }
  }

#pragma unroll
  for (int i = 0; i < 4; i++)
#pragma unroll
    for (int j = 0; j < 4; j++)
#pragma unroll
      for (int r = 0; r < 4; r++) {
        int row = row0 + wr * 64 + i * 16 + quad * 4 + r;
        int col = col0 + wc * 64 + j * 16 + l16;
        float v = acc[i][j][r];
        if constexpr (MODE == 0 || MODE == 3) {
          u16* q = (u16*)dst;
          int bh = ((row >> 11) << 4) | (col >> 6);
          if constexpr (MODE == 3) v *= 0.125f;  // 1/sqrt(dh)
          q[(bh * SEQ + (row & 2047)) * DHEAD + (col & 63)] = f2bf(v);
        } else if constexpr (MODE == 1) {
          u16* q = (u16*)dst;
          int bh = ((row >> 11) << 4) | (col >> 6);
          q[(bh * DHEAD + (col & 63)) * SEQ + (row & 2047)] = f2bf(v);
        } else {
          ((float*)dst)[row * DMODEL + col] = v;
        }
      }
}

// ---------------- Flash attention (causal), v2 ----------------
// Q (pre-scaled): [B*H, L, dh] bf16; K: [B*H, L, dh]; Vt: [B*H, dh, L]; Ao: [B, L, H*dh] bf16
// 256 thr = 4 waves; block = 128 q-rows of one (b,h); wave owns 32 rows (2 rt tiles).
// K/V tiles (64 keys) staged in LDS once per block, register-prefetched one tile ahead.
// Softmax row reductions via DPP (no ds_swizzle latency). LPT block ordering (qt desc).
__global__ __launch_bounds__(256, 3) void attn_kernel(const u16* __restrict__ Q,
                                                      const u16* __restrict__ Kk,
                                                      const u16* __restrict__ Vt,
                                                      u16* __restrict__ Ao) {
  constexpr int STR = 72;  // padded LDS stride (shorts), 144 B: 16B-aligned, <=2-way banks
  __shared__ u16 Ks[64 * STR];
  __shared__ u16 Vs[64 * STR];
  __shared__ u16 Plds[4][32 * STR];
  const int tid = threadIdx.x;
  const int lane = tid & 63;
  const int w = tid >> 6;
  const int quad = lane >> 4, l16 = lane & 15;
  const int bh = blockIdx.x & 63;
  const int qt = 15 - (blockIdx.x >> 6);  // LPT: heaviest q-tiles dispatched first
  const int b = bh >> 4, h = bh & 15;
  const u16* Qh = Q + bh * SEQ * DHEAD;
  const u16* Kh = Kk + bh * SEQ * DHEAD;
  const u16* Vh = Vt + bh * DHEAD * SEQ;
  const int q0w = qt * 128 + w * 32;
  const int nkt = 2 * qt + 2;  // block's causal k-tile count

  // Q fragments (A layout: m=l16, k=quad*8+j), resident
  bf16x8 qf[2][2];
#pragma unroll
  for (int rt = 0; rt < 2; rt++)
#pragma unroll
    for (int ks = 0; ks < 2; ks++)
      qf[rt][ks] = *reinterpret_cast<const bf16x8*>(
          &Qh[(q0w + rt * 16 + l16) * DHEAD + ks * 32 + quad * 8]);

  f32x4 o[2][4] = {};
  float m_i[2][4], l_i[2][4];
#pragma unroll
  for (int rt = 0; rt < 2; rt++)
#pragma unroll
    for (int r = 0; r < 4; r++) { m_i[rt][r] = -1e30f; l_i[rt][r] = 0.f; }

  // staging: 256 thr × 2 chunks × 16B cover one 64×64 bf16 tile for K and V
  const int srow = tid >> 3;        // 0..31
  const int scol = (tid & 7) * 8;   // 0..56
  bf16x8 kst[2], vst[2];
  auto load_tile = [&](int kb) {
#pragma unroll
    for (int c = 0; c < 2; c++) {
      int r = srow + c * 32;
      kst[c] = *reinterpret_cast<const bf16x8*>(&Kh[(kb + r) * DHEAD + scol]);
      vst[c] = *reinterpret_cast<const bf16x8*>(&Vh[r * SEQ + kb + scol]);
    }
  };
  auto store_tile = [&]() {
#pragma unroll
    for (int c = 0; c < 2; c++) {
      int r = srow + c * 32;
      *reinterpret_cast<bf16x8*>(&Ks[r * STR + scol]) = kst[c];
      *reinterpret_cast<bf16x8*>(&Vs[r * STR + scol]) = vst[c];
    }
  };

  load_tile(0);
  store_tile();
  __syncthreads();

  for (int kt = 0; kt < nkt; kt++) {
    const int kbase = kt * 64;
    const bool have_next = (kt + 1 < nkt);
    if (have_next) load_tile(kbase + 64);  // prefetch into regs, in flight during compute

    if (kbase <= q0w + 31) {  // wave-uniform causal skip
      // ---- S = Q K^T, both rt tiles (K frags read once) ----
      f32x4 s[2][4];
#pragma unroll
      for (int nt = 0; nt < 4; nt++) {
        bf16x8 kf0 = *reinterpret_cast<const bf16x8*>(&Ks[(nt * 16 + l16) * STR + quad * 8]);
        bf16x8 kf1 = *reinterpret_cast<const bf16x8*>(&Ks[(nt * 16 + l16) * STR + 32 + quad * 8]);
#pragma unroll
        for (int rt = 0; rt < 2; rt++) {
          f32x4 z = {0.f, 0.f, 0.f, 0.f};
          z = MFMA16x16x32(qf[rt][0], kf0, z);
          s[rt][nt] = MFMA16x16x32(qf[rt][1], kf1, z);
        }
      }
      // ---- causal mask (only diagonal tiles) ----
      if (kbase + 63 > q0w) {
#pragma unroll
        for (int rt = 0; rt < 2; rt++)
#pragma unroll
          for (int nt = 0; nt < 4; nt++)
#pragma unroll
            for (int r = 0; r < 4; r++) {
              int qrow = q0w + rt * 16 + quad * 4 + r;
              int kcol = kbase + nt * 16 + l16;
              if (kcol > qrow) s[rt][nt][r] = -1e30f;
            }
      }
      // ---- online softmax (DPP row reductions; scale pre-folded into Q) ----
      float alpha[2][4];
#pragma unroll
      for (int rt = 0; rt < 2; rt++)
#pragma unroll
        for (int r = 0; r < 4; r++) {
          float mx = fmaxf(fmaxf(s[rt][0][r], s[rt][1][r]), fmaxf(s[rt][2][r], s[rt][3][r]));
          mx = rowmax16(mx);
          float mnew = fmaxf(m_i[rt][r], mx);
          alpha[rt][r] = __expf(m_i[rt][r] - mnew);
          m_i[rt][r] = mnew;
        }
#pragma unroll
      for (int rt = 0; rt < 2; rt++)
#pragma unroll
        for (int nt = 0; nt < 4; nt++)
#pragma unroll
          for (int r = 0; r < 4; r++)
            s[rt][nt][r] = __expf(s[rt][nt][r] - m_i[rt][r]);
#pragma unroll
      for (int rt = 0; rt < 2; rt++)
#pragma unroll
        for (int r = 0; r < 4; r++) {
          float rs = (s[rt][0][r] + s[rt][1][r]) + (s[rt][2][r] + s[rt][3][r]);
          rs = rowsum16(rs);
          l_i[rt][r] = l_i[rt][r] * alpha[rt][r] + rs;
        }
#pragma unroll
      for (int rt = 0; rt < 2; rt++)
#pragma unroll
        for (int nt = 0; nt < 4; nt++)
#pragma unroll
          for (int r = 0; r < 4; r++) o[rt][nt][r] *= alpha[rt][r];
      // ---- P: C-layout -> A-layout via per-wave LDS region ----
      u16* Pw = Plds[w];
#pragma unroll
      for (int rt = 0; rt < 2; rt++)
#pragma unroll
        for (int nt = 0; nt < 4; nt++)
#pragma unroll
          for (int r = 0; r < 4; r++)
            Pw[(rt * 16 + quad * 4 + r) * STR + nt * 16 + l16] = f2bf(s[rt][nt][r]);
      asm volatile("s_waitcnt lgkmcnt(0)" ::: "memory");
      bf16x8 pa[2][2];
#pragma unroll
      for (int rt = 0; rt < 2; rt++)
#pragma unroll
        for (int hh = 0; hh < 2; hh++)
          pa[rt][hh] = *reinterpret_cast<const bf16x8*>(
              &Pw[(rt * 16 + l16) * STR + hh * 32 + quad * 8]);
      // ---- O += P V (V frags read once, used by both rt) ----
#pragma unroll
      for (int nt2 = 0; nt2 < 4; nt2++) {
        bf16x8 vf0 = *reinterpret_cast<const bf16x8*>(&Vs[(nt2 * 16 + l16) * STR + quad * 8]);
        bf16x8 vf1 = *reinterpret_cast<const bf16x8*>(&Vs[(nt2 * 16 + l16) * STR + 32 + quad * 8]);
#pragma unroll
        for (int rt = 0; rt < 2; rt++) {
          o[rt][nt2] = MFMA16x16x32(pa[rt][0], vf0, o[rt][nt2]);
          o[rt][nt2] = MFMA16x16x32(pa[rt][1], vf1, o[rt][nt2]);
        }
      }
    }

    if (have_next) {
      __syncthreads();   // all waves done reading Ks/Vs of tile kt
      store_tile();      // commit prefetched tile kt+1
      __syncthreads();
    }
  }

  // ---- epilogue ----
#pragma unroll
  for (int rt = 0; rt < 2; rt++)
#pragma unroll
    for (int nt2 = 0; nt2 < 4; nt2++)
#pragma unroll
      for (int r = 0; r < 4; r++) {
        int qrow = q0w + rt * 16 + quad * 4 + r;
        float v = o[rt][nt2][r] / l_i[rt][r];
        Ao[(b * SEQ + qrow) * DMODEL + h * DHEAD + nt2 * 16 + l16] = f2bf(v);
      }
}

// ---------------- launch ----------------
extern "C" void kernel_launch(void* const* d_in, const int* in_sizes, int n_in,
                              void* d_out, int out_size, void* d_ws, size_t ws_size,
                              hipStream_t stream) {
  const float* x = (const float*)d_in[0];
  const float* Wq = (const float*)d_in[1];
  const float* Wk = (const float*)d_in[2];
  const float* Wv = (const float*)d_in[3];
  const float* Wo = (const float*)d_in[4];
  float* out = (float*)d_out;

  u16* xb  = (u16*)d_ws;
  u16* wqb = xb  + MROWS * DMODEL;
  u16* wkb = wqb + DMODEL * DMODEL;
  u16* wvb = wkb + DMODEL * DMODEL;
  u16* wob = wvb + DMODEL * DMODEL;
  u16* qb  = wob + DMODEL * DMODEL;  // [B,H,L,dh], pre-scaled
  u16* kb  = qb  + MROWS * DMODEL;
  u16* vtb = kb  + MROWS * DMODEL;   // [B,H,dh,L]
  u16* aob = vtb + MROWS * DMODEL;   // [B,L,D]

  {
    int n4 = MROWS * DMODEL / 4;
    cvt_f32_bf16<<<n4 / 256, 256, 0, stream>>>(x, xb, n4);
    int w4 = DMODEL * DMODEL / 4;
    cvt_f32_bf16<<<w4 / 256, 256, 0, stream>>>(Wq, wqb, w4);
    cvt_f32_bf16<<<w4 / 256, 256, 0, stream>>>(Wk, wkb, w4);
    cvt_f32_bf16<<<w4 / 256, 256, 0, stream>>>(Wv, wvb, w4);
    cvt_f32_bf16<<<w4 / 256, 256, 0, stream>>>(Wo, wob, w4);
  }

  dim3 ggrid(DMODEL / 128, MROWS / 128);
  gemm_bt<3><<<ggrid, 256, 0, stream>>>(xb, wqb, (void*)qb);   // Q, scaled
  gemm_bt<0><<<ggrid, 256, 0, stream>>>(xb, wkb, (void*)kb);
  gemm_bt<1><<<ggrid, 256, 0, stream>>>(xb, wvb, (void*)vtb);

  attn_kernel<<<BATCH * NHEADS * (SEQ / 128), 256, 0, stream>>>(qb, kb, vtb, aob);

  gemm_bt<2><<<ggrid, 256, 0, stream>>>(aob, wob, (void*)out);
}